// Round 4
// baseline (620.539 us; speedup 1.0000x reference)
//
#include <hip/hip_runtime.h>
#include <cstdint>

typedef float f32x4 __attribute__((ext_vector_type(4)));
typedef __bf16 bf16x8 __attribute__((ext_vector_type(8)));
typedef unsigned int uint32;
typedef unsigned short ushort_t;

__device__ __forceinline__ ushort_t f2bf(float f) {
    uint32 u = __builtin_bit_cast(uint32, f);
    u = (u + 0x7fffu + ((u >> 16) & 1u)) >> 16;   // RNE
    return (ushort_t)u;
}
__device__ __forceinline__ float bf2f(ushort_t h) {
    return __builtin_bit_cast(float, (uint32)h << 16);
}

// ---------------------------------------------------------------------------
// im2col for conv1: NCHW fp32 -> P[px][32] bf16 patches (27 taps + 5 zero pad)
// ---------------------------------------------------------------------------
__global__ __launch_bounds__(256) void im2col1_kernel(
    const float* __restrict__ in,   // [4][3][512][512]
    ushort_t* __restrict__ P)       // [4*512*512][32]
{
    int px = blockIdx.x * 256 + threadIdx.x;
    int n = px >> 18, rem = px & 262143;
    int y = rem >> 9, x = rem & 511;
    ushort_t pv[32];
#pragma unroll
    for (int ci = 0; ci < 3; ++ci)
#pragma unroll
        for (int t = 0; t < 9; ++t) {
            int dy = t / 3 - 1, dx = t % 3 - 1;
            int yy = y + dy, xx = x + dx;
            bool v = ((unsigned)yy < 512u) && ((unsigned)xx < 512u);
            pv[ci * 9 + t] = v ? f2bf(in[((n * 3 + ci) * 512 + yy) * 512 + xx])
                               : (ushort_t)0;
        }
#pragma unroll
    for (int k = 27; k < 32; ++k) pv[k] = 0;
    uint4* dst = (uint4*)(P + (size_t)px * 32);
    dst[0] = *(uint4*)(pv);
    dst[1] = *(uint4*)(pv + 8);
    dst[2] = *(uint4*)(pv + 16);
    dst[3] = *(uint4*)(pv + 24);
}

// ---------------------------------------------------------------------------
// conv1 weights -> MFMA-A fragment order [nt][lane][8], K padded 27->32
// ---------------------------------------------------------------------------
__global__ void prepw1_kernel(const float* __restrict__ w1,
                              ushort_t* __restrict__ Wsw1)
{
    int i = blockIdx.x * 256 + threadIdx.x;   // 2048 total
    int ii = i & 7, lane = (i >> 3) & 63, nt = i >> 9;
    int cout = nt * 16 + (lane & 15);
    int k = (lane >> 4) * 8 + ii;
    Wsw1[i] = (k < 27) ? f2bf(w1[cout * 27 + k]) : (ushort_t)0;
}

// ---------------------------------------------------------------------------
// gemm1: X1[px][64] = W1[64][32] @ P[px][32]^T + b1 + fused BN stats
// ---------------------------------------------------------------------------
__global__ __launch_bounds__(256) void gemm1_kernel(
    const ushort_t* __restrict__ P,     // [Mpx][32]
    const ushort_t* __restrict__ Wsw1,  // [4][64][8]
    const float* __restrict__ b1,
    ushort_t* __restrict__ X1,          // [Mpx][64]
    float* __restrict__ stats)          // [32][128]
{
    __shared__ float sred[4][128];
    int tid = threadIdx.x;
    int wave = tid >> 6, lane = tid & 63;
    int lp = lane & 15, lg = lane >> 4;
    int pxb = blockIdx.x * 256 + wave * 64;

    bf16x8 wf[4];
#pragma unroll
    for (int nt = 0; nt < 4; ++nt)
        wf[nt] = *(const bf16x8*)(Wsw1 + (nt * 64 + lane) * 8);

    f32x4 acc[4][4];
#pragma unroll
    for (int a = 0; a < 4; ++a)
#pragma unroll
        for (int b = 0; b < 4; ++b) acc[a][b] = (f32x4){0.f, 0.f, 0.f, 0.f};

#pragma unroll
    for (int nf = 0; nf < 4; ++nf) {
        bf16x8 bfrag = *(const bf16x8*)(P + (size_t)(pxb + nf * 16 + lp) * 32 + lg * 8);
#pragma unroll
        for (int nt = 0; nt < 4; ++nt)
            acc[nt][nf] = __builtin_amdgcn_mfma_f32_16x16x32_bf16(
                wf[nt], bfrag, acc[nt][nf], 0, 0, 0);
    }

    float s16[16], q16[16];
#pragma unroll
    for (int j = 0; j < 16; ++j) { s16[j] = 0.f; q16[j] = 0.f; }

#pragma unroll
    for (int nf = 0; nf < 4; ++nf) {
        size_t px = (size_t)pxb + nf * 16 + lp;
#pragma unroll
        for (int nt = 0; nt < 4; ++nt) {
            ushort_t ov[4];
#pragma unroll
            for (int r = 0; r < 4; ++r) {
                float o = acc[nt][nf][r] + b1[nt * 16 + lg * 4 + r];
                s16[nt * 4 + r] += o;
                q16[nt * 4 + r] += o * o;
                ov[r] = f2bf(o);
            }
            *(ushort4*)(X1 + px * 64 + nt * 16 + lg * 4) = *(ushort4*)ov;
        }
    }

#pragma unroll
    for (int off = 1; off < 16; off <<= 1)
#pragma unroll
        for (int j = 0; j < 16; ++j) {
            s16[j] += __shfl_xor(s16[j], off);
            q16[j] += __shfl_xor(q16[j], off);
        }
    if (lp == 0) {
#pragma unroll
        for (int nt = 0; nt < 4; ++nt)
#pragma unroll
            for (int r = 0; r < 4; ++r) {
                int ch = nt * 16 + lg * 4 + r;
                sred[wave][ch]      = s16[nt * 4 + r];
                sred[wave][64 + ch] = q16[nt * 4 + r];
            }
    }
    __syncthreads();
    if (tid < 128) {
        float tot = sred[0][tid] + sred[1][tid] + sred[2][tid] + sred[3][tid];
        atomicAdd(&stats[(blockIdx.x & 31) * 128 + tid], tot);
    }
}

// ---------------------------------------------------------------------------
// finalize: sum 32 buckets -> scale/shift
// ---------------------------------------------------------------------------
__global__ void finalize_kernel(const float* __restrict__ stats,
                                const float* __restrict__ gamma,
                                const float* __restrict__ beta,
                                float inv_cnt, float* __restrict__ scsh)
{
    int c = threadIdx.x;  // 64
    float S = 0.f, Q = 0.f;
    for (int b = 0; b < 32; ++b) {
        S += stats[b * 128 + c];
        Q += stats[b * 128 + 64 + c];
    }
    float mean = S * inv_cnt;
    float var  = Q * inv_cnt - mean * mean;
    float rs   = rsqrtf(var + 1e-5f);
    float sc   = gamma[c] * rs;
    scsh[c]      = sc;
    scsh[64 + c] = beta[c] - mean * sc;
}

// ---------------------------------------------------------------------------
// weight swizzle into MFMA-A fragment order: [tap][kc][nt][lane][8]
// value = w[cout][cin][tap] * scale[cin]  (scale==null -> 1)
// ---------------------------------------------------------------------------
__global__ __launch_bounds__(256) void prepw_kernel(
    const float* __restrict__ w, const float* __restrict__ scale,
    ushort_t* __restrict__ Wsw, int CIN)
{
    int i = blockIdx.x * 256 + threadIdx.x;
    int KC = CIN >> 5;
    int ii = i & 7, lane = (i >> 3) & 63, nt = (i >> 9) & 3;
    int rest = i >> 11;
    int kc = rest % KC, t = rest / KC;
    if (t >= 9) return;
    int cout = nt * 16 + (lane & 15);
    int cin  = kc * 32 + (lane >> 4) * 8 + ii;
    float v = w[(cout * CIN + cin) * 9 + t];
    if (scale) v *= scale[cin];
    Wsw[i] = f2bf(v);
}

// T[t][cout] = sum_cin w2[cout][cin][t] * shift[cin]; Tsum[cout] at T+576
__global__ void prepT_kernel(const float* __restrict__ w2,
                             const float* __restrict__ shift,
                             float* __restrict__ T)
{
    int idx = threadIdx.x;   // 576
    if (idx < 576) {
        int t = idx / 64, cout = idx % 64;
        float s = 0.f;
        for (int cin = 0; cin < 64; ++cin)
            s += w2[(cout * 64 + cin) * 9 + t] * shift[cin];
        T[idx] = s;
    }
    __syncthreads();
    if (idx < 64) {
        float s = 0.f;
        for (int t = 0; t < 9; ++t) s += T[t * 64 + idx];
        T[576 + idx] = s;
    }
}

// ---------------------------------------------------------------------------
// Marching double-buffered implicit-GEMM conv 3x3 SAME, CIN->64.
// Block = 4 waves = 4-row strip x (TILES*64) cols. Stages = TILES * (CIN/32):
// per stage: issue next-stage global loads -> regs, compute current chunk
// (9 taps x 16 MFMA/wave) from LDS, ds_write regs -> other buffer, barrier.
// 32-ch chunks => pixel row = 64B => ds reads/writes naturally conflict-free.
// Fused BN-stats (per-tile shuffle reduce -> LDS accumulate -> 1 atomic).
// ---------------------------------------------------------------------------
template <int CIN, bool HAS_T, int HH, int WW, int TILES>
__global__ __launch_bounds__(256, 3) void conv_mfma3_kernel(
    const ushort_t* __restrict__ X,    // NHWC bf16 [N*H*W][CIN]
    const ushort_t* __restrict__ Wsw,  // [9][CIN/32][4][64][8]
    const float* __restrict__ T,       // [9*64 + 64] or null
    const float* __restrict__ bias,    // [64]
    ushort_t* __restrict__ Y,          // NHWC bf16 [N*H*W][64]
    float* __restrict__ stats)         // [32][128]
{
    constexpr int KC     = CIN >> 5;           // 32-ch chunks (== prepw KC)
    constexpr int STAGES = TILES * KC;
    constexpr int CSTR   = WW / (64 * TILES);
    constexpr int RSTR   = HH >> 2;
    constexpr int NLD    = 1584;               // 6*66 px * 4 quads

    __shared__ ushort_t lds0[12672];           // 6*66*32 ch = 25344 B
    __shared__ ushort_t lds1[12672];
    __shared__ float sred[4][128];

    int nwg = gridDim.x;
    int bid = blockIdx.x;
    int cpx = nwg >> 3;
    int bs  = (bid & 7) * cpx + (bid >> 3);    // XCD-contiguous swizzle

    int tid  = threadIdx.x;
    int wave = tid >> 6, lane = tid & 63;
    int lp = lane & 15, lg = lane >> 4;

    int tmp = bs;
    int cs = tmp % CSTR;  tmp /= CSTR;
    int rs = tmp % RSTR;
    int n  = tmp / RSTR;
    int y0 = rs << 2, x0 = cs * (64 * TILES);
    int y  = y0 + wave;

    for (int i = tid; i < 512; i += 256) ((float*)sred)[i] = 0.f;

    f32x4 acc[4][4];
#pragma unroll
    for (int a = 0; a < 4; ++a)
#pragma unroll
        for (int b = 0; b < 4; ++b) acc[a][b] = (f32x4){0.f, 0.f, 0.f, 0.f};

    uint4 rbuf[7];

    auto issue_stage = [&](int s) {
        int tj = s / KC, c = s - tj * KC;
        int xt = x0 + tj * 64;
#pragma unroll
        for (int j = 0; j < 7; ++j) {
            int idx = tid + j * 256;
            uint4 v = {0u, 0u, 0u, 0u};
            if (idx < NLD) {
                int p  = idx >> 2;
                int ry = p / 66, cx = p - ry * 66;
                int gy = y0 - 1 + ry, gx = xt - 1 + cx;
                if (((unsigned)gy < (unsigned)HH) && ((unsigned)gx < (unsigned)WW))
                    v = *(const uint4*)(X + ((size_t)(n * HH + gy) * WW + gx) * CIN
                                          + c * 32 + (idx & 3) * 8);
            }
            rbuf[j] = v;
        }
    };
    auto write_stage = [&](ushort_t* buf) {
#pragma unroll
        for (int j = 0; j < 7; ++j) {
            int idx = tid + j * 256;
            if (idx < NLD) ((uint4*)buf)[idx] = rbuf[j];
        }
    };

    // prologue: stage 0
    issue_stage(0);
    write_stage(lds0);
    __syncthreads();

    ushort_t* cur = lds0;
    ushort_t* nxt = lds1;

#pragma unroll 1
    for (int s = 0; s < STAGES; ++s) {
        int tj = s / KC, c = s - tj * KC;
        if (s + 1 < STAGES) issue_stage(s + 1);

        // ---- compute chunk c of tile tj from cur ----
#pragma unroll
        for (int t = 0; t < 9; ++t) {
            const int dy = t / 3 - 1, dx = t % 3 - 1;
            bf16x8 wf[4];
#pragma unroll
            for (int nt = 0; nt < 4; ++nt)
                wf[nt] = *(const bf16x8*)(Wsw + (size_t)(((t * KC + c) << 2) + nt) * 512 + lane * 8);
            int prow = (wave + 1 + dy) * 66 + (1 + dx) + lp;
#pragma unroll
            for (int nf = 0; nf < 4; ++nf) {
                int px = prow + nf * 16;
                bf16x8 bfrag = *(const bf16x8*)((const char*)cur + px * 64 + lg * 16);
#pragma unroll
                for (int nt = 0; nt < 4; ++nt)
                    acc[nt][nf] = __builtin_amdgcn_mfma_f32_16x16x32_bf16(
                        wf[nt], bfrag, acc[nt][nf], 0, 0, 0);
            }
        }

        // ---- tile epilogue after last chunk ----
        if (c == KC - 1) {
            int xt = x0 + tj * 64;
            bool top = (y == 0), bot = (y == HH - 1);
            float s16[16], q16[16];
            size_t rowbase = ((size_t)(n * HH + y) * WW) * 64;
#pragma unroll
            for (int nf = 0; nf < 4; ++nf) {
                int x = xt + nf * 16 + lp;
                bool lft = (x == 0), rgt = (x == WW - 1);
                bool edge = top | bot | lft | rgt;
#pragma unroll
                for (int nt = 0; nt < 4; ++nt) {
                    ushort_t ov[4];
#pragma unroll
                    for (int r = 0; r < 4; ++r) {
                        int ch = nt * 16 + lg * 4 + r;
                        float o = acc[nt][nf][r] + bias[ch];
                        if (HAS_T) {
                            o += T[576 + ch];
                            if (edge) {
#pragma unroll
                                for (int t = 0; t < 9; ++t) {
                                    int dy = t / 3 - 1, dx = t % 3 - 1;
                                    bool miss = (top && dy < 0) || (bot && dy > 0) ||
                                                (lft && dx < 0) || (rgt && dx > 0);
                                    if (miss) o -= T[t * 64 + ch];
                                }
                            }
                        }
                        if (nf == 0) { s16[nt * 4 + r] = o; q16[nt * 4 + r] = o * o; }
                        else         { s16[nt * 4 + r] += o; q16[nt * 4 + r] += o * o; }
                        ov[r] = f2bf(o);
                    }
                    *(ushort4*)(Y + rowbase + (size_t)x * 64 + nt * 16 + lg * 4) = *(ushort4*)ov;
                }
            }
#pragma unroll
            for (int off = 1; off < 16; off <<= 1)
#pragma unroll
                for (int j = 0; j < 16; ++j) {
                    s16[j] += __shfl_xor(s16[j], off);
                    q16[j] += __shfl_xor(q16[j], off);
                }
            if (lp == 0) {
#pragma unroll
                for (int nt = 0; nt < 4; ++nt)
#pragma unroll
                    for (int r = 0; r < 4; ++r) {
                        int ch = nt * 16 + lg * 4 + r;
                        sred[wave][ch]      += s16[nt * 4 + r];
                        sred[wave][64 + ch] += q16[nt * 4 + r];
                    }
            }
            // reset accumulators for next tile
#pragma unroll
            for (int a = 0; a < 4; ++a)
#pragma unroll
                for (int b = 0; b < 4; ++b) acc[a][b] = (f32x4){0.f, 0.f, 0.f, 0.f};
        }

        if (s + 1 < STAGES) write_stage(nxt);
        __syncthreads();
        ushort_t* t2 = cur; cur = nxt; nxt = t2;
    }

    if (tid < 128) {
        float tot = sred[0][tid] + sred[1][tid] + sred[2][tid] + sred[3][tid];
        atomicAdd(&stats[(bs & 31) * 128 + tid], tot);
    }
}

// ---------------------------------------------------------------------------
// BN2 + ReLU -> skip_con (NCHW fp32) + Haar DWT -> X3 (NHWC bf16, 256 ch)
// ---------------------------------------------------------------------------
__global__ __launch_bounds__(256) void bn2_dwt_skip_kernel(
    const ushort_t* __restrict__ X2, const float* __restrict__ scsh,
    float* __restrict__ skip,     // [4][64][512][512]
    ushort_t* __restrict__ X3)    // [4][256][256][256]
{
    __shared__ float v[128][65];
    int tid = threadIdx.x;
    int b = blockIdx.x;
    int n  = b >> 11;
    int r2 = b & 2047;
    int y0 = (r2 >> 3) << 1;
    int x0 = (r2 & 7) << 6;

#pragma unroll
    for (int k = 0; k < 4; ++k) {
        int q  = tid + k * 256;
        int px = q >> 3;
        int cb = (q & 7) * 8;
        int gy = y0 + (px >> 6);
        int gx = x0 + (px & 63);
        uint4 raw = *(const uint4*)(X2 + ((size_t)(n * 512 + gy) * 512 + gx) * 64 + cb);
        const ushort_t* up = (const ushort_t*)&raw;
#pragma unroll
        for (int j = 0; j < 8; ++j) {
            float f = bf2f(up[j]);
            float o = f * scsh[cb + j] + scsh[64 + cb + j];
            v[px][cb + j] = fmaxf(o, 0.f);
        }
    }
    __syncthreads();

    {
        int c = tid >> 2, sub = tid & 3;
#pragma unroll
        for (int rr = 0; rr < 2; ++rr) {
            float* orow = skip + ((size_t)(n * 64 + c) * 512 + (y0 + rr)) * 512 + x0;
#pragma unroll
            for (int qq = 0; qq < 4; ++qq) {
                int xb = qq * 16 + sub * 4;
                float4 w4;
                w4.x = v[rr * 64 + xb + 0][c];
                w4.y = v[rr * 64 + xb + 1][c];
                w4.z = v[rr * 64 + xb + 2][c];
                w4.w = v[rr * 64 + xb + 3][c];
                *(float4*)(orow + xb) = w4;
            }
        }
    }
    {
        int c = tid & 63, jj = tid >> 6;
        int yq = y0 >> 1, xq = x0 >> 1;
#pragma unroll
        for (int it = 0; it < 8; ++it) {
            int xl = jj * 8 + it;
            float x00 = v[2 * xl][c],      x01 = v[2 * xl + 1][c];
            float x10 = v[64 + 2 * xl][c], x11 = v[64 + 2 * xl + 1][c];
            float cA = (x00 + x01 + x10 + x11) * 0.5f;
            float cH = (x00 + x01 - x10 - x11) * 0.5f;
            float cV = (x00 - x01 + x10 - x11) * 0.5f;
            float cD = (x00 - x01 - x10 + x11) * 0.5f;
            ushort_t* dst = X3 + ((size_t)(n * 256 + yq) * 256 + xq + xl) * 256 + c;
            dst[0]   = f2bf(cA);
            dst[64]  = f2bf(cH);
            dst[128] = f2bf(cV);
            dst[192] = f2bf(cD);
        }
    }
}

// ---------------------------------------------------------------------------
// BN3 + ReLU -> dwt_out (NCHW fp32)
// ---------------------------------------------------------------------------
__global__ __launch_bounds__(256) void bn3_kernel(
    const ushort_t* __restrict__ X4, const float* __restrict__ scsh,
    float* __restrict__ out)   // [4][64][256][256]
{
    __shared__ float v[64][65];
    int tid = threadIdx.x;
    int b = blockIdx.x;
    int n  = b >> 10;
    int r2 = b & 1023;
    int y  = r2 >> 2;
    int x0 = (r2 & 3) << 6;

#pragma unroll
    for (int k = 0; k < 2; ++k) {
        int q  = tid + k * 256;
        int px = q >> 3;
        int cb = (q & 7) * 8;
        uint4 raw = *(const uint4*)(X4 + ((size_t)(n * 256 + y) * 256 + x0 + px) * 64 + cb);
        const ushort_t* up = (const ushort_t*)&raw;
#pragma unroll
        for (int j = 0; j < 8; ++j) {
            float f = bf2f(up[j]);
            float o = f * scsh[cb + j] + scsh[64 + cb + j];
            v[px][cb + j] = fmaxf(o, 0.f);
        }
    }
    __syncthreads();
    int c = tid >> 2, sub = tid & 3;
    float* orow = out + ((size_t)(n * 64 + c) * 256 + y) * 256 + x0;
#pragma unroll
    for (int qq = 0; qq < 4; ++qq) {
        int xb = qq * 16 + sub * 4;
        float4 w4;
        w4.x = v[xb + 0][c];
        w4.y = v[xb + 1][c];
        w4.z = v[xb + 2][c];
        w4.w = v[xb + 3][c];
        *(float4*)(orow + xb) = w4;
    }
}

// ---------------------------------------------------------------------------
extern "C" void kernel_launch(void* const* d_in, const int* in_sizes, int n_in,
                              void* d_out, int out_size, void* d_ws, size_t ws_size,
                              hipStream_t stream)
{
    const float* in  = (const float*)d_in[0];
    const float* w1  = (const float*)d_in[1];
    const float* b1  = (const float*)d_in[2];
    const float* g1  = (const float*)d_in[3];
    const float* be1 = (const float*)d_in[4];
    const float* w2  = (const float*)d_in[5];
    const float* b2  = (const float*)d_in[6];
    const float* g2  = (const float*)d_in[7];
    const float* be2 = (const float*)d_in[8];
    const float* w3  = (const float*)d_in[9];
    const float* b3  = (const float*)d_in[10];
    const float* g3  = (const float*)d_in[11];
    const float* be3 = (const float*)d_in[12];

    float* out     = (float*)d_out;
    float* dwt_out = out;              // 4*64*256*256
    float* skip    = out + 16777216;   // 4*64*512*512

    char* ws = (char*)d_ws;
    ushort_t* X1 = (ushort_t*)ws;                       // 134,217,728 B
    ushort_t* X2 = (ushort_t*)(ws + 134217728);         // 134,217,728 B
    ushort_t* P  = X2;                                  // im2col patches alias X2
    ushort_t* X3 = X1;                                  // reuse
    ushort_t* X4 = X2;                                  // reuse
    char* aux = ws + 268435456;
    float* stats1 = (float*)(aux);                      // 32*128*4 = 16384 B
    float* stats2 = (float*)(aux + 16384);
    float* stats3 = (float*)(aux + 32768);
    float* scsh1  = (float*)(aux + 49152);
    float* scsh2  = (float*)(aux + 49664);
    float* scsh3  = (float*)(aux + 50176);
    float* T2     = (float*)(aux + 50688);              // 640 floats
    ushort_t* Wsw2 = (ushort_t*)(aux + 57344);          // 73,728 B
    ushort_t* Wsw3 = (ushort_t*)(aux + 131072);         // 294,912 B
    ushort_t* Wsw1 = (ushort_t*)(aux + 425984);         // 4,096 B

    hipMemsetAsync(aux, 0, 49152, stream);

    im2col1_kernel<<<4096, 256, 0, stream>>>(in, P);
    prepw1_kernel<<<8, 256, 0, stream>>>(w1, Wsw1);
    gemm1_kernel<<<4096, 256, 0, stream>>>(P, Wsw1, b1, X1, stats1);
    finalize_kernel<<<1, 64, 0, stream>>>(stats1, g1, be1, 1.f / 1048576.f, scsh1);
    prepw_kernel<<<144, 256, 0, stream>>>(w2, scsh1, Wsw2, 64);
    prepT_kernel<<<1, 576, 0, stream>>>(w2, scsh1 + 64, T2);

    // conv2: 4-row x 256-col strips (TILES=4), 1024 blocks, 8 stages each
    conv_mfma3_kernel<64, true, 512, 512, 4><<<1024, 256, 0, stream>>>(
        X1, Wsw2, T2, b2, X2, stats2);
    finalize_kernel<<<1, 64, 0, stream>>>(stats2, g2, be2, 1.f / 1048576.f, scsh2);

    bn2_dwt_skip_kernel<<<8192, 256, 0, stream>>>(X2, scsh2, skip, X3);

    prepw_kernel<<<576, 256, 0, stream>>>(w3, nullptr, Wsw3, 256);
    // conv3: 4-row x 64-col strips (TILES=1), 1024 blocks, 8 stages each
    conv_mfma3_kernel<256, false, 256, 256, 1><<<1024, 256, 0, stream>>>(
        X3, Wsw3, nullptr, b3, X4, stats3);
    finalize_kernel<<<1, 64, 0, stream>>>(stats3, g3, be3, 1.f / 262144.f, scsh3);

    bn3_kernel<<<4096, 256, 0, stream>>>(X4, scsh3, dwt_out);
}

// Round 5
// 552.928 us; speedup vs baseline: 1.1223x; 1.1223x over previous
//
#include <hip/hip_runtime.h>
#include <cstdint>

typedef float f32x4 __attribute__((ext_vector_type(4)));
typedef __bf16 bf16x8 __attribute__((ext_vector_type(8)));
typedef unsigned int uint32;
typedef unsigned short ushort_t;

__device__ __forceinline__ ushort_t f2bf(float f) {
    uint32 u = __builtin_bit_cast(uint32, f);
    u = (u + 0x7fffu + ((u >> 16) & 1u)) >> 16;   // RNE
    return (ushort_t)u;
}
__device__ __forceinline__ float bf2f(ushort_t h) {
    return __builtin_bit_cast(float, (uint32)h << 16);
}

// ---------------------------------------------------------------------------
// im2col for conv1: NCHW fp32 -> P[px][32] bf16 patches (27 taps + 5 zero pad)
// ---------------------------------------------------------------------------
__global__ __launch_bounds__(256) void im2col1_kernel(
    const float* __restrict__ in,   // [4][3][512][512]
    ushort_t* __restrict__ P)       // [4*512*512][32]
{
    int px = blockIdx.x * 256 + threadIdx.x;
    int n = px >> 18, rem = px & 262143;
    int y = rem >> 9, x = rem & 511;
    ushort_t pv[32];
#pragma unroll
    for (int ci = 0; ci < 3; ++ci)
#pragma unroll
        for (int t = 0; t < 9; ++t) {
            int dy = t / 3 - 1, dx = t % 3 - 1;
            int yy = y + dy, xx = x + dx;
            bool v = ((unsigned)yy < 512u) && ((unsigned)xx < 512u);
            pv[ci * 9 + t] = v ? f2bf(in[((n * 3 + ci) * 512 + yy) * 512 + xx])
                               : (ushort_t)0;
        }
#pragma unroll
    for (int k = 27; k < 32; ++k) pv[k] = 0;
    uint4* dst = (uint4*)(P + (size_t)px * 32);
    dst[0] = *(uint4*)(pv);
    dst[1] = *(uint4*)(pv + 8);
    dst[2] = *(uint4*)(pv + 16);
    dst[3] = *(uint4*)(pv + 24);
}

// ---------------------------------------------------------------------------
// conv1 weights -> MFMA-A fragment order [nt][lane][8], K padded 27->32
// ---------------------------------------------------------------------------
__global__ void prepw1_kernel(const float* __restrict__ w1,
                              ushort_t* __restrict__ Wsw1)
{
    int i = blockIdx.x * 256 + threadIdx.x;   // 2048 total
    int ii = i & 7, lane = (i >> 3) & 63, nt = i >> 9;
    int cout = nt * 16 + (lane & 15);
    int k = (lane >> 4) * 8 + ii;
    Wsw1[i] = (k < 27) ? f2bf(w1[cout * 27 + k]) : (ushort_t)0;
}

// ---------------------------------------------------------------------------
// gemm1: X1[px][64] = W1[64][32] @ P[px][32]^T + b1 + fused BN stats
// ---------------------------------------------------------------------------
__global__ __launch_bounds__(256) void gemm1_kernel(
    const ushort_t* __restrict__ P,     // [Mpx][32]
    const ushort_t* __restrict__ Wsw1,  // [4][64][8]
    const float* __restrict__ b1,
    ushort_t* __restrict__ X1,          // [Mpx][64]
    float* __restrict__ stats)          // [32][128]
{
    __shared__ float sred[4][128];
    int tid = threadIdx.x;
    int wave = tid >> 6, lane = tid & 63;
    int lp = lane & 15, lg = lane >> 4;
    int pxb = blockIdx.x * 256 + wave * 64;

    bf16x8 wf[4];
#pragma unroll
    for (int nt = 0; nt < 4; ++nt)
        wf[nt] = *(const bf16x8*)(Wsw1 + (nt * 64 + lane) * 8);

    f32x4 acc[4][4];
#pragma unroll
    for (int a = 0; a < 4; ++a)
#pragma unroll
        for (int b = 0; b < 4; ++b) acc[a][b] = (f32x4){0.f, 0.f, 0.f, 0.f};

#pragma unroll
    for (int nf = 0; nf < 4; ++nf) {
        bf16x8 bfrag = *(const bf16x8*)(P + (size_t)(pxb + nf * 16 + lp) * 32 + lg * 8);
#pragma unroll
        for (int nt = 0; nt < 4; ++nt)
            acc[nt][nf] = __builtin_amdgcn_mfma_f32_16x16x32_bf16(
                wf[nt], bfrag, acc[nt][nf], 0, 0, 0);
    }

    float s16[16], q16[16];
#pragma unroll
    for (int j = 0; j < 16; ++j) { s16[j] = 0.f; q16[j] = 0.f; }

#pragma unroll
    for (int nf = 0; nf < 4; ++nf) {
        size_t px = (size_t)pxb + nf * 16 + lp;
#pragma unroll
        for (int nt = 0; nt < 4; ++nt) {
            ushort_t ov[4];
#pragma unroll
            for (int r = 0; r < 4; ++r) {
                float o = acc[nt][nf][r] + b1[nt * 16 + lg * 4 + r];
                s16[nt * 4 + r] += o;
                q16[nt * 4 + r] += o * o;
                ov[r] = f2bf(o);
            }
            *(ushort4*)(X1 + px * 64 + nt * 16 + lg * 4) = *(ushort4*)ov;
        }
    }

#pragma unroll
    for (int off = 1; off < 16; off <<= 1)
#pragma unroll
        for (int j = 0; j < 16; ++j) {
            s16[j] += __shfl_xor(s16[j], off);
            q16[j] += __shfl_xor(q16[j], off);
        }
    if (lp == 0) {
#pragma unroll
        for (int nt = 0; nt < 4; ++nt)
#pragma unroll
            for (int r = 0; r < 4; ++r) {
                int ch = nt * 16 + lg * 4 + r;
                sred[wave][ch]      = s16[nt * 4 + r];
                sred[wave][64 + ch] = q16[nt * 4 + r];
            }
    }
    __syncthreads();
    if (tid < 128) {
        float tot = sred[0][tid] + sred[1][tid] + sred[2][tid] + sred[3][tid];
        atomicAdd(&stats[(blockIdx.x & 31) * 128 + tid], tot);
    }
}

// ---------------------------------------------------------------------------
// finalize: sum 32 buckets -> scale/shift
// ---------------------------------------------------------------------------
__global__ void finalize_kernel(const float* __restrict__ stats,
                                const float* __restrict__ gamma,
                                const float* __restrict__ beta,
                                float inv_cnt, float* __restrict__ scsh)
{
    int c = threadIdx.x;  // 64
    float S = 0.f, Q = 0.f;
    for (int b = 0; b < 32; ++b) {
        S += stats[b * 128 + c];
        Q += stats[b * 128 + 64 + c];
    }
    float mean = S * inv_cnt;
    float var  = Q * inv_cnt - mean * mean;
    float rs   = rsqrtf(var + 1e-5f);
    float sc   = gamma[c] * rs;
    scsh[c]      = sc;
    scsh[64 + c] = beta[c] - mean * sc;
}

// ---------------------------------------------------------------------------
// weight swizzle into MFMA-A fragment order: [tap][kc][nt][lane][8]
// value = w[cout][cin][tap] * scale[cin]  (scale==null -> 1)
// ---------------------------------------------------------------------------
__global__ __launch_bounds__(256) void prepw_kernel(
    const float* __restrict__ w, const float* __restrict__ scale,
    ushort_t* __restrict__ Wsw, int CIN)
{
    int i = blockIdx.x * 256 + threadIdx.x;
    int KC = CIN >> 5;
    int ii = i & 7, lane = (i >> 3) & 63, nt = (i >> 9) & 3;
    int rest = i >> 11;
    int kc = rest % KC, t = rest / KC;
    if (t >= 9) return;
    int cout = nt * 16 + (lane & 15);
    int cin  = kc * 32 + (lane >> 4) * 8 + ii;
    float v = w[(cout * CIN + cin) * 9 + t];
    if (scale) v *= scale[cin];
    Wsw[i] = f2bf(v);
}

// T[t][cout] = sum_cin w2[cout][cin][t] * shift[cin]; Tsum[cout] at T+576
__global__ void prepT_kernel(const float* __restrict__ w2,
                             const float* __restrict__ shift,
                             float* __restrict__ T)
{
    int idx = threadIdx.x;   // 576
    if (idx < 576) {
        int t = idx / 64, cout = idx % 64;
        float s = 0.f;
        for (int cin = 0; cin < 64; ++cin)
            s += w2[(cout * 64 + cin) * 9 + t] * shift[cin];
        T[idx] = s;
    }
    __syncthreads();
    if (idx < 64) {
        float s = 0.f;
        for (int t = 0; t < 9; ++t) s += T[t * 64 + idx];
        T[576 + idx] = s;
    }
}

// ---------------------------------------------------------------------------
// LDS-tiled implicit-GEMM conv 3x3 SAME, CIN->64, bf16 MFMA 16x16x32.
// Block = 4 waves; output tile = 4 rows x 64 cols x 64 couts.
// Per 32-ch chunk: stage 6x66 halo tile in CHANNEL-PLANE-MAJOR LDS layout
// [4 planes][396 px][8ch] (25.3 KB): each 16-lane group reads/writes 256 B
// contiguous -> balanced 8 accesses/bank, conflict-free, no swizzle.
// 2 barriers per chunk. Fused BN-stats epilogue.
// ---------------------------------------------------------------------------
template <int CIN, bool HAS_T, int HH, int WW>
__global__ __launch_bounds__(256, 4) void conv_mfma4_kernel(
    const ushort_t* __restrict__ X,    // NHWC bf16 [N*H*W][CIN]
    const ushort_t* __restrict__ Wsw,  // [9][CIN/32][4][64][8]
    const float* __restrict__ T,       // [9*64 + 64] or null
    const float* __restrict__ bias,    // [64]
    ushort_t* __restrict__ Y,          // NHWC bf16 [N*H*W][64]
    float* __restrict__ stats)         // [32][128]
{
    constexpr int KC     = CIN >> 5;   // number of 32-ch chunks
    constexpr int COLS_B = WW >> 6;
    constexpr int ROWS_B = HH >> 2;

    __shared__ ushort_t tile[12672];   // [4][396][8] = 25344 B
    __shared__ float sred[4][128];

    int nwg = gridDim.x;
    int bid = blockIdx.x;
    int cpx = nwg >> 3;
    int bs  = (bid & 7) * cpx + (bid >> 3);   // XCD-contiguous swizzle

    int tid  = threadIdx.x;
    int wave = tid >> 6, lane = tid & 63;
    int lp = lane & 15, lg = lane >> 4;

    int tmp = bs;
    int ctile = tmp % COLS_B;  tmp /= COLS_B;
    int rtile = tmp % ROWS_B;
    int n     = tmp / ROWS_B;
    int y0 = rtile << 2, x0 = ctile << 6;
    int y  = y0 + wave;

    f32x4 acc[4][4];
#pragma unroll
    for (int a = 0; a < 4; ++a)
#pragma unroll
        for (int b = 0; b < 4; ++b) acc[a][b] = (f32x4){0.f, 0.f, 0.f, 0.f};

#pragma unroll 1
    for (int c = 0; c < KC; ++c) {
        if (c) __syncthreads();
        // ---- stage chunk c: [4 planes][396 px][8ch], zero-padded halo ----
#pragma unroll
        for (int j = 0; j < 7; ++j) {
            int s = tid + j * 256;
            if (s < 1584) {
                int px = s >> 2, cb = s & 3;
                int ry = px / 66, cx = px - ry * 66;
                int gy = y0 - 1 + ry, gx = x0 - 1 + cx;
                uint4 v = {0u, 0u, 0u, 0u};
                if (((unsigned)gy < (unsigned)HH) && ((unsigned)gx < (unsigned)WW))
                    v = *(const uint4*)(X + ((size_t)(n * HH + gy) * WW + gx) * CIN
                                          + c * 32 + cb * 8);
                *(uint4*)(tile + cb * 3168 + px * 8) = v;
            }
        }
        __syncthreads();

        // ---- compute: 9 taps x 16 MFMA over this chunk ----
#pragma unroll
        for (int t = 0; t < 9; ++t) {
            const int dy = t / 3 - 1, dx = t % 3 - 1;
            bf16x8 wf[4];
#pragma unroll
            for (int nt = 0; nt < 4; ++nt)
                wf[nt] = *(const bf16x8*)(Wsw + (size_t)(((t * KC + c) << 2) + nt) * 512 + lane * 8);
            int prow = (wave + 1 + dy) * 66 + (1 + dx) + lp;
#pragma unroll
            for (int nf = 0; nf < 4; ++nf) {
                int px = prow + nf * 16;
                bf16x8 bfrag = *(const bf16x8*)(tile + lg * 3168 + px * 8);
#pragma unroll
                for (int nt = 0; nt < 4; ++nt)
                    acc[nt][nf] = __builtin_amdgcn_mfma_f32_16x16x32_bf16(
                        wf[nt], bfrag, acc[nt][nf], 0, 0, 0);
            }
        }
    }

    // ---- epilogue: bias (+T border fix), store, fused stats ----
    bool top = (y == 0), bot = (y == HH - 1);
    float s16[16], q16[16];
#pragma unroll
    for (int j = 0; j < 16; ++j) { s16[j] = 0.f; q16[j] = 0.f; }

    size_t rowbase = ((size_t)(n * HH + y) * WW) * 64;
#pragma unroll
    for (int nf = 0; nf < 4; ++nf) {
        int x = x0 + nf * 16 + lp;
        bool lft = (x == 0), rgt = (x == WW - 1);
        bool edge = top | bot | lft | rgt;
#pragma unroll
        for (int nt = 0; nt < 4; ++nt) {
            ushort_t ov[4];
#pragma unroll
            for (int r = 0; r < 4; ++r) {
                int ch = nt * 16 + lg * 4 + r;
                float o = acc[nt][nf][r] + bias[ch];
                if (HAS_T) {
                    o += T[576 + ch];
                    if (edge) {
#pragma unroll
                        for (int t = 0; t < 9; ++t) {
                            int dy = t / 3 - 1, dx = t % 3 - 1;
                            bool miss = (top && dy < 0) || (bot && dy > 0) ||
                                        (lft && dx < 0) || (rgt && dx > 0);
                            if (miss) o -= T[t * 64 + ch];
                        }
                    }
                }
                s16[nt * 4 + r] += o;
                q16[nt * 4 + r] += o * o;
                ov[r] = f2bf(o);
            }
            *(ushort4*)(Y + rowbase + (size_t)x * 64 + nt * 16 + lg * 4) = *(ushort4*)ov;
        }
    }

#pragma unroll
    for (int off = 1; off < 16; off <<= 1)
#pragma unroll
        for (int j = 0; j < 16; ++j) {
            s16[j] += __shfl_xor(s16[j], off);
            q16[j] += __shfl_xor(q16[j], off);
        }
    if (lp == 0) {
#pragma unroll
        for (int nt = 0; nt < 4; ++nt)
#pragma unroll
            for (int r = 0; r < 4; ++r) {
                int ch = nt * 16 + lg * 4 + r;
                sred[wave][ch]      = s16[nt * 4 + r];
                sred[wave][64 + ch] = q16[nt * 4 + r];
            }
    }
    __syncthreads();
    if (tid < 128) {
        float tot = sred[0][tid] + sred[1][tid] + sred[2][tid] + sred[3][tid];
        atomicAdd(&stats[(bs & 31) * 128 + tid], tot);
    }
}

// ---------------------------------------------------------------------------
// BN2 + ReLU -> skip_con (NCHW fp32) + Haar DWT -> X3 (NHWC bf16, 256 ch)
// ---------------------------------------------------------------------------
__global__ __launch_bounds__(256) void bn2_dwt_skip_kernel(
    const ushort_t* __restrict__ X2, const float* __restrict__ scsh,
    float* __restrict__ skip,     // [4][64][512][512]
    ushort_t* __restrict__ X3)    // [4][256][256][256]
{
    __shared__ float v[128][65];
    int tid = threadIdx.x;
    int b = blockIdx.x;
    int n  = b >> 11;
    int r2 = b & 2047;
    int y0 = (r2 >> 3) << 1;
    int x0 = (r2 & 7) << 6;

#pragma unroll
    for (int k = 0; k < 4; ++k) {
        int q  = tid + k * 256;
        int px = q >> 3;
        int cb = (q & 7) * 8;
        int gy = y0 + (px >> 6);
        int gx = x0 + (px & 63);
        uint4 raw = *(const uint4*)(X2 + ((size_t)(n * 512 + gy) * 512 + gx) * 64 + cb);
        const ushort_t* up = (const ushort_t*)&raw;
#pragma unroll
        for (int j = 0; j < 8; ++j) {
            float f = bf2f(up[j]);
            float o = f * scsh[cb + j] + scsh[64 + cb + j];
            v[px][cb + j] = fmaxf(o, 0.f);
        }
    }
    __syncthreads();

    {
        int c = tid >> 2, sub = tid & 3;
#pragma unroll
        for (int rr = 0; rr < 2; ++rr) {
            float* orow = skip + ((size_t)(n * 64 + c) * 512 + (y0 + rr)) * 512 + x0;
#pragma unroll
            for (int qq = 0; qq < 4; ++qq) {
                int xb = qq * 16 + sub * 4;
                float4 w4;
                w4.x = v[rr * 64 + xb + 0][c];
                w4.y = v[rr * 64 + xb + 1][c];
                w4.z = v[rr * 64 + xb + 2][c];
                w4.w = v[rr * 64 + xb + 3][c];
                *(float4*)(orow + xb) = w4;
            }
        }
    }
    {
        int c = tid & 63, jj = tid >> 6;
        int yq = y0 >> 1, xq = x0 >> 1;
#pragma unroll
        for (int it = 0; it < 8; ++it) {
            int xl = jj * 8 + it;
            float x00 = v[2 * xl][c],      x01 = v[2 * xl + 1][c];
            float x10 = v[64 + 2 * xl][c], x11 = v[64 + 2 * xl + 1][c];
            float cA = (x00 + x01 + x10 + x11) * 0.5f;
            float cH = (x00 + x01 - x10 - x11) * 0.5f;
            float cV = (x00 - x01 + x10 - x11) * 0.5f;
            float cD = (x00 - x01 - x10 + x11) * 0.5f;
            ushort_t* dst = X3 + ((size_t)(n * 256 + yq) * 256 + xq + xl) * 256 + c;
            dst[0]   = f2bf(cA);
            dst[64]  = f2bf(cH);
            dst[128] = f2bf(cV);
            dst[192] = f2bf(cD);
        }
    }
}

// ---------------------------------------------------------------------------
// BN3 + ReLU -> dwt_out (NCHW fp32)
// ---------------------------------------------------------------------------
__global__ __launch_bounds__(256) void bn3_kernel(
    const ushort_t* __restrict__ X4, const float* __restrict__ scsh,
    float* __restrict__ out)   // [4][64][256][256]
{
    __shared__ float v[64][65];
    int tid = threadIdx.x;
    int b = blockIdx.x;
    int n  = b >> 10;
    int r2 = b & 1023;
    int y  = r2 >> 2;
    int x0 = (r2 & 3) << 6;

#pragma unroll
    for (int k = 0; k < 2; ++k) {
        int q  = tid + k * 256;
        int px = q >> 3;
        int cb = (q & 7) * 8;
        uint4 raw = *(const uint4*)(X4 + ((size_t)(n * 256 + y) * 256 + x0 + px) * 64 + cb);
        const ushort_t* up = (const ushort_t*)&raw;
#pragma unroll
        for (int j = 0; j < 8; ++j) {
            float f = bf2f(up[j]);
            float o = f * scsh[cb + j] + scsh[64 + cb + j];
            v[px][cb + j] = fmaxf(o, 0.f);
        }
    }
    __syncthreads();
    int c = tid >> 2, sub = tid & 3;
    float* orow = out + ((size_t)(n * 64 + c) * 256 + y) * 256 + x0;
#pragma unroll
    for (int qq = 0; qq < 4; ++qq) {
        int xb = qq * 16 + sub * 4;
        float4 w4;
        w4.x = v[xb + 0][c];
        w4.y = v[xb + 1][c];
        w4.z = v[xb + 2][c];
        w4.w = v[xb + 3][c];
        *(float4*)(orow + xb) = w4;
    }
}

// ---------------------------------------------------------------------------
extern "C" void kernel_launch(void* const* d_in, const int* in_sizes, int n_in,
                              void* d_out, int out_size, void* d_ws, size_t ws_size,
                              hipStream_t stream)
{
    const float* in  = (const float*)d_in[0];
    const float* w1  = (const float*)d_in[1];
    const float* b1  = (const float*)d_in[2];
    const float* g1  = (const float*)d_in[3];
    const float* be1 = (const float*)d_in[4];
    const float* w2  = (const float*)d_in[5];
    const float* b2  = (const float*)d_in[6];
    const float* g2  = (const float*)d_in[7];
    const float* be2 = (const float*)d_in[8];
    const float* w3  = (const float*)d_in[9];
    const float* b3  = (const float*)d_in[10];
    const float* g3  = (const float*)d_in[11];
    const float* be3 = (const float*)d_in[12];

    float* out     = (float*)d_out;
    float* dwt_out = out;              // 4*64*256*256
    float* skip    = out + 16777216;   // 4*64*512*512

    char* ws = (char*)d_ws;
    ushort_t* X1 = (ushort_t*)ws;                       // 134,217,728 B
    ushort_t* X2 = (ushort_t*)(ws + 134217728);         // 134,217,728 B
    ushort_t* P  = X2;                                  // im2col patches alias X2
    ushort_t* X3 = X1;                                  // reuse
    ushort_t* X4 = X2;                                  // reuse
    char* aux = ws + 268435456;
    float* stats1 = (float*)(aux);                      // 32*128*4 = 16384 B
    float* stats2 = (float*)(aux + 16384);
    float* stats3 = (float*)(aux + 32768);
    float* scsh1  = (float*)(aux + 49152);
    float* scsh2  = (float*)(aux + 49664);
    float* scsh3  = (float*)(aux + 50176);
    float* T2     = (float*)(aux + 50688);              // 640 floats
    ushort_t* Wsw2 = (ushort_t*)(aux + 57344);          // 73,728 B
    ushort_t* Wsw3 = (ushort_t*)(aux + 131072);         // 294,912 B
    ushort_t* Wsw1 = (ushort_t*)(aux + 425984);         // 4,096 B

    hipMemsetAsync(aux, 0, 49152, stream);

    im2col1_kernel<<<4096, 256, 0, stream>>>(in, P);
    prepw1_kernel<<<8, 256, 0, stream>>>(w1, Wsw1);
    gemm1_kernel<<<4096, 256, 0, stream>>>(P, Wsw1, b1, X1, stats1);
    finalize_kernel<<<1, 64, 0, stream>>>(stats1, g1, be1, 1.f / 1048576.f, scsh1);
    prepw_kernel<<<144, 256, 0, stream>>>(w2, scsh1, Wsw2, 64);
    prepT_kernel<<<1, 576, 0, stream>>>(w2, scsh1 + 64, T2);

    conv_mfma4_kernel<64, true, 512, 512><<<4096, 256, 0, stream>>>(
        X1, Wsw2, T2, b2, X2, stats2);
    finalize_kernel<<<1, 64, 0, stream>>>(stats2, g2, be2, 1.f / 1048576.f, scsh2);

    bn2_dwt_skip_kernel<<<8192, 256, 0, stream>>>(X2, scsh2, skip, X3);

    prepw_kernel<<<576, 256, 0, stream>>>(w3, nullptr, Wsw3, 256);
    conv_mfma4_kernel<256, false, 256, 256><<<1024, 256, 0, stream>>>(
        X3, Wsw3, nullptr, b3, X4, stats3);
    finalize_kernel<<<1, 64, 0, stream>>>(stats3, g3, be3, 1.f / 262144.f, scsh3);

    bn3_kernel<<<4096, 256, 0, stream>>>(X4, scsh3, dwt_out);
}